// Round 8
// baseline (1786.894 us; speedup 1.0000x reference)
//
#include <hip/hip_runtime.h>
#include <math.h>

#define B_ 64
#define SEQ_ 720
#define PRED_ 336
#define C_ 862
#define PLEN_ 96
#define HID_ 256

// workspace layout (float offsets)
#define OFF_WCOMB  0
#define OFF_F0     (OFF_WCOMB + SEQ_*PRED_)
#define OFF_COLSUM (OFF_F0 + PLEN_*PRED_)
#define OFF_BIAS   (OFF_COLSUM + PRED_)
#define OFF_WPACK  (OFF_BIAS + PRED_)
#define OFF_F0B    (OFF_WPACK + HID_*8)
#define WS_EXACT_FLOATS (OFF_F0B + B_*PLEN_*PRED_)

// ---------------- prep kernels (tiny) ----------------
// Wcomb[u,p] = sw[u,p] + (A^T (tw-sw))[u,p], A = edge-replicated 25-tap mean matrix.
// A[t,u]*25: interior 1 for |t-u|<=12; col u=0 total = 13-t (t<=12); col u=719 total = t-706 (t>=707).
__global__ void prep_w_k(const float* __restrict__ sw, const float* __restrict__ tw,
                         float* __restrict__ Wcomb) {
  int idx = blockIdx.x * 256 + threadIdx.x;
  if (idx >= SEQ_ * PRED_) return;
  int u = idx / PRED_;
  int p = idx - u * PRED_;
  int lo = u - 12; if (lo < 0) lo = 0;
  int hi = u + 12; if (hi > SEQ_ - 1) hi = SEQ_ - 1;
  float s = 0.f;
  for (int t = lo; t <= hi; ++t) s += tw[t*PRED_ + p] - sw[t*PRED_ + p];
  if (u == 0) {
    for (int t = 0; t <= 12; ++t)
      s += (float)(12 - t) * (tw[t*PRED_ + p] - sw[t*PRED_ + p]);
  }
  if (u == SEQ_ - 1) {
    for (int t = SEQ_ - 13; t <= SEQ_ - 1; ++t)
      s += (float)(t - (SEQ_ - 13)) * (tw[t*PRED_ + p] - sw[t*PRED_ + p]);
  }
  Wcomb[idx] = sw[idx] + s * (1.f / 25.f);
}

// Fallback fold (periodic assumption): F0[d,p] = sum over u ≡ d (mod 96) of Wcomb[u,p]
__global__ void prep_fold_k(const float* __restrict__ Wcomb, float* __restrict__ F0) {
  int idx = blockIdx.x * 256 + threadIdx.x;
  if (idx >= PLEN_ * PRED_) return;
  int d = idx / PRED_;
  int p = idx - d * PRED_;
  float s = 0.f;
  for (int u = d; u < SEQ_; u += PLEN_) s += Wcomb[u*PRED_ + p];
  F0[idx] = s;
}

// Exact per-batch fold: F0B[b][r][p] = sum over {u : gi_b(u)==r} Wcomb[u,p],
// where gi_b(u) = trunc(fmodf(idxf_b + (float)u, 96)) — the reference's exact
// float index math (robust to half-ULP rounding across integer boundaries).
__global__ __launch_bounds__(384) void prep_foldb_k(const float* __restrict__ Wcomb,
                                                    const float* __restrict__ x_mark,
                                                    float* __restrict__ F0B) {
  __shared__ int   scnt[PLEN_];
  __shared__ short slist[PLEN_][16];
  const int b   = blockIdx.x;
  const int tid = threadIdx.x;
  const float idxf = x_mark[((size_t)b*SEQ_ + (SEQ_-1)) * 4] * (float)PLEN_;

  if (tid < PLEN_) scnt[tid] = 0;
  __syncthreads();
  for (int u = tid; u < SEQ_; u += 384) {
    int r = (int)fmodf(idxf + (float)u, (float)PLEN_);
    r = r < 0 ? 0 : (r > PLEN_-1 ? PLEN_-1 : r);
    int slot = atomicAdd(&scnt[r], 1);
    if (slot < 16) slist[r][slot] = (short)u;
  }
  __syncthreads();
  // deterministic order: insertion-sort each r-list (n <= ~10)
  if (tid < PLEN_) {
    const int n = scnt[tid] < 16 ? scnt[tid] : 16;
    for (int i = 1; i < n; ++i) {
      short v = slist[tid][i];
      int k = i - 1;
      while (k >= 0 && slist[tid][k] > v) { slist[tid][k+1] = slist[tid][k]; --k; }
      slist[tid][k+1] = v;
    }
  }
  __syncthreads();
  if (tid < PRED_) {
    float* o = F0B + (size_t)b * PLEN_ * PRED_;
    for (int r = 0; r < PLEN_; ++r) {
      const int n = scnt[r] < 16 ? scnt[r] : 16;
      float s = 0.f;
      for (int i = 0; i < n; ++i)
        s += Wcomb[(int)slist[r][i] * PRED_ + tid];
      o[r*PRED_ + tid] = s;
    }
  }
}

__global__ void prep_small_k(const float* __restrict__ Wcomb,
                             const float* __restrict__ sb, const float* __restrict__ tb,
                             const float* __restrict__ w1, const float* __restrict__ b1,
                             const float* __restrict__ w2,
                             float* __restrict__ colsum, float* __restrict__ biasPT,
                             float* __restrict__ wpack) {
  int tid = threadIdx.x;
  if (tid < PRED_) {
    float s = 0.f;
    for (int u = 0; u < SEQ_; ++u) s += Wcomb[u*PRED_ + tid];
    colsum[tid] = s;                 // == sum_u Wcomb[u,p] == sum_t tw[t,p]
    biasPT[tid] = sb[tid] + tb[tid];
  }
  if (tid < HID_) {
    wpack[tid*8 + 0] = w1[tid];          // w1[0][j]
    wpack[tid*8 + 1] = w1[HID_ + tid];   // w1[1][j]
    wpack[tid*8 + 2] = w1[2*HID_ + tid]; // w1[2][j]
    wpack[tid*8 + 3] = b1[tid];
    wpack[tid*8 + 4] = w2[tid*3 + 0];
    wpack[tid*8 + 5] = w2[tid*3 + 1];
    wpack[tid*8 + 6] = w2[tid*3 + 2];
    wpack[tid*8 + 7] = 0.f;
  }
}

// ---------------- fused main kernel ----------------
// One block = (batch b, 16-channel tile). 256 threads: tc = tid&3 (4 c-groups of
// 4 contiguous c), tp = tid>>2 (64 p-threads, p = tp + 64*jj, jj<6; p>=336 lives
// in zero-padded LDS columns and is masked from wsum/store).
// RevIN stats are computed in-block during phase-1 staging (each staging thread
// sees all 45 rows u = kuS + 16k of its channel -> Σv, Σv² partials).
__global__ __launch_bounds__(256, 3) void fused_k(
    const float* __restrict__ x, const float* __restrict__ x_mark,
    const float* __restrict__ pattern, const float* __restrict__ wsf,
    const float* __restrict__ b2g, float* __restrict__ out, const int exact)
{
  __shared__ float sW[16][384];   // staged Wcomb/F0 rows, cols 336..383 zero pad
  __shared__ float sX[16][16];    // staged x / pattern rows for this c-tile
  __shared__ float sRed[64][48];  // wsum reduction over tp (also stats scratch)
  __shared__ float sWavg[48];     // w_avg[c_local][k]
  __shared__ float sStats[16][4]; // mean, istd, std per local channel

  const int tid = threadIdx.x;
  const int tc = tid & 3;
  const int tp = tid >> 2;
  const int b  = blockIdx.y;
  const int c0 = blockIdx.x * 16;

  const float* __restrict__ Wcomb  = wsf + OFF_WCOMB;
  const float* __restrict__ colsum = wsf + OFF_COLSUM;
  const float* __restrict__ biasPT = wsf + OFF_BIAS;
  const float* __restrict__ F0use  = exact
      ? (wsf + OFF_F0B + (size_t)b * PLEN_ * PRED_)
      : (wsf + OFF_F0);

  const float idxf = x_mark[((size_t)b*SEQ_ + (SEQ_-1)) * 4] * (float)PLEN_;

  // zero the pad columns of sW once (staging never writes pp>=336)
  for (int i = tid; i < 16*48; i += 256) sW[i/48][336 + (i % 48)] = 0.f;

  const int kuS = tid >> 4, ccS = tid & 15;
  const int cS = c0 + ccS;
  const bool cSv = (cS < C_);

  // ---- phase 1: acc[p,c] = sum_u x[b,u,c] * Wcomb[u,p]; stats alongside ----
  float acc[6][4];
  #pragma unroll
  for (int jj = 0; jj < 6; ++jj)
    #pragma unroll
    for (int j = 0; j < 4; ++j) acc[jj][j] = 0.f;

  float ps = 0.f, psq = 0.f;

  for (int u0 = 0; u0 < SEQ_; u0 += 16) {
    {
      const float v = cSv ? x[((size_t)b*SEQ_ + u0 + kuS)*C_ + cS] : 0.f;
      sX[kuS][ccS] = v;
      ps += v;
      psq = fmaf(v, v, psq);
    }
    {
      const float* __restrict__ Wp = Wcomb + (size_t)u0 * PRED_;
      int i = tid, ku = 0, pp = tid;
      #pragma unroll
      for (int it = 0; it < 21; ++it) {   // 16*336/256 == 21 exactly
        sW[ku][pp] = Wp[i];
        i += 256; pp += 256;
        int wrap = (pp >= PRED_);
        pp -= wrap ? PRED_ : 0;
        ku += wrap;
      }
    }
    __syncthreads();
    #pragma unroll
    for (int ku = 0; ku < 16; ++ku) {
      const float4 xv = *(const float4*)&sX[ku][tc*4];
      #pragma unroll
      for (int jj = 0; jj < 6; ++jj) {
        const float wv = sW[ku][tp + 64*jj];
        acc[jj][0] = fmaf(wv, xv.x, acc[jj][0]);
        acc[jj][1] = fmaf(wv, xv.y, acc[jj][1]);
        acc[jj][2] = fmaf(wv, xv.z, acc[jj][2]);
        acc[jj][3] = fmaf(wv, xv.w, acc[jj][3]);
      }
    }
    __syncthreads();
  }

  // ---- stats reduction: 16 partials per channel -> mean/istd/std ----
  {
    float* red = &sRed[0][0];
    red[tid]       = ps;
    red[256 + tid] = psq;
    __syncthreads();
    if (tid < 16) {
      float s = 0.f, sq = 0.f;
      #pragma unroll
      for (int k = 0; k < 16; ++k) {
        s  += red[k*16 + tid];
        sq += red[256 + k*16 + tid];
      }
      const float mean = s * (1.f / (float)SEQ_);
      const float var  = (sq - s * s * (1.f / (float)SEQ_)) * (1.f / (float)(SEQ_ - 1));
      const float stdv = sqrtf(var + 1e-5f);
      sStats[tid][0] = mean;
      sStats[tid][1] = 1.f / stdv;
      sStats[tid][2] = stdv;
    }
    __syncthreads();
  }

  // ---- phase 2: corr[p,c] = sum_r F0use[r,p] * pattern[row(r), c] ----
  // exact path: F0use is per-batch folded on actual gi -> row(r) = r.
  // fallback:   F0use is residue-folded -> row(r) = trunc(fmodf(idxf + r, 96)).
  float cr[6][4];
  #pragma unroll
  for (int jj = 0; jj < 6; ++jj)
    #pragma unroll
    for (int j = 0; j < 4; ++j) cr[jj][j] = 0.f;

  for (int d0 = 0; d0 < PLEN_; d0 += 16) {
    {
      int rr;
      if (exact) {
        rr = d0 + kuS;
      } else {
        rr = (int)fmodf(idxf + (float)(d0 + kuS), (float)PLEN_);
        rr = rr < 0 ? 0 : (rr > PLEN_-1 ? PLEN_-1 : rr);
      }
      sX[kuS][ccS] = cSv ? pattern[(size_t)rr*C_ + cS] : 0.f;
    }
    {
      const float* __restrict__ Fp = F0use + (size_t)d0 * PRED_;
      int i = tid, ku = 0, pp = tid;
      #pragma unroll
      for (int it = 0; it < 21; ++it) {
        sW[ku][pp] = Fp[i];
        i += 256; pp += 256;
        int wrap = (pp >= PRED_);
        pp -= wrap ? PRED_ : 0;
        ku += wrap;
      }
    }
    __syncthreads();
    #pragma unroll
    for (int kd = 0; kd < 16; ++kd) {
      const float4 pv = *(const float4*)&sX[kd][tc*4];
      #pragma unroll
      for (int jj = 0; jj < 6; ++jj) {
        const float fv = sW[kd][tp + 64*jj];
        cr[jj][0] = fmaf(fv, pv.x, cr[jj][0]);
        cr[jj][1] = fmaf(fv, pv.y, cr[jj][1]);
        cr[jj][2] = fmaf(fv, pv.z, cr[jj][2]);
        cr[jj][3] = fmaf(fv, pv.w, cr[jj][3]);
      }
    }
    __syncthreads();
  }

  // ---- epilogue: pred / y1 / pattern-gather ----
  float mean_c[4], istd_c[4], std_c[4];
  #pragma unroll
  for (int j = 0; j < 4; ++j) {
    const int cl = tc*4 + j;
    mean_c[j] = sStats[cl][0];
    istd_c[j] = sStats[cl][1];
    std_c[j]  = sStats[cl][2];
  }
  float colv[6], biasv[6];
  #pragma unroll
  for (int jj = 0; jj < 6; ++jj) {
    int p = tp + 64*jj; if (p > PRED_-1) p = PRED_-1;
    colv[jj] = colsum[p]; biasv[jj] = biasPT[p];
  }

  float qv[6][4];
  const float w2f = fmodf(idxf + (float)SEQ_, (float)PLEN_);
  #pragma unroll
  for (int jj = 0; jj < 6; ++jj) {
    const int p = tp + 64*jj;
    int r2 = (int)fmodf(w2f + (float)p, (float)PLEN_);
    r2 = r2 < 0 ? 0 : (r2 > PLEN_-1 ? PLEN_-1 : r2);
    #pragma unroll
    for (int j = 0; j < 4; ++j) {
      int c = c0 + tc*4 + j; if (c > C_-1) c = C_-1;
      qv[jj][j] = pattern[(size_t)r2*C_ + c];
      const float t  = fmaf(-mean_c[j], colv[jj], acc[jj][j]);
      const float pr = fmaf(istd_c[j], t, biasv[jj]);
      acc[jj][j] = pr;              // pred
      cr[jj][j]  = pr - cr[jj][j];  // y1 = pred - corr
    }
  }

  // ---- phase 3: per-element MLP (3 -> 256 relu -> 3 softmax), accumulate wsum ----
  // Loop order: jj outer, m (hidden) middle, j (4 channels) inner-unrolled.
  // Weight loads (thread-uniform -> s_load) amortized over 4 channels: 2 loads
  // + 28 VALU per m instead of 8 loads + 28 VALU.
  const float4* __restrict__ wp4 = (const float4*)(wsf + OFF_WPACK);
  const float b20 = b2g[0], b21 = b2g[1], b22 = b2g[2];
  const int njj = (tp < 16) ? 6 : 5;   // wave-uniform: lanes 0..63 all have tp<16
  float wsum[4][3];
  #pragma unroll
  for (int j = 0; j < 4; ++j) { wsum[j][0] = 0.f; wsum[j][1] = 0.f; wsum[j][2] = 0.f; }

  for (int jj = 0; jj < njj; ++jj) {
    float L[4][3];
    #pragma unroll
    for (int j = 0; j < 4; ++j) { L[j][0] = b20; L[j][1] = b21; L[j][2] = b22; }

    #pragma unroll 2
    for (int m = 0; m < HID_; ++m) {
      const float4 wa = wp4[2*m];      // {w1[0,j], w1[1,j], w1[2,j], b1[j]}
      const float4 wb = wp4[2*m + 1];  // {w2[j,0], w2[j,1], w2[j,2], 0}
      #pragma unroll
      for (int j = 0; j < 4; ++j) {
        float h = fmaf(acc[jj][j], wa.x, wa.w);
        h = fmaf(cr[jj][j], wa.y, h);
        h = fmaf(qv[jj][j], wa.z, h);
        h = fmaxf(h, 0.f);
        L[j][0] = fmaf(h, wb.x, L[j][0]);
        L[j][1] = fmaf(h, wb.y, L[j][1]);
        L[j][2] = fmaf(h, wb.z, L[j][2]);
      }
    }
    #pragma unroll
    for (int j = 0; j < 4; ++j) {
      const float mx = fmaxf(L[j][0], fmaxf(L[j][1], L[j][2]));
      const float e0 = __expf(L[j][0] - mx), e1 = __expf(L[j][1] - mx),
                  e2 = __expf(L[j][2] - mx);
      const float inv = 1.f / (e0 + e1 + e2);
      wsum[j][0] += e0 * inv;
      wsum[j][1] += e1 * inv;
      wsum[j][2] += e2 * inv;
    }
  }

  // ---- reduce wsum over the 64 p-threads -> w_avg[c_local][k] ----
  __syncthreads();   // sRed was reused for stats; ensure those reads are done
  #pragma unroll
  for (int j = 0; j < 4; ++j) {
    sRed[tp][tc*12 + j*3 + 0] = wsum[j][0];
    sRed[tp][tc*12 + j*3 + 1] = wsum[j][1];
    sRed[tp][tc*12 + j*3 + 2] = wsum[j][2];
  }
  __syncthreads();
  if (tid < 48) {
    const int cl = tid / 3, k = tid - cl*3;
    const int col = (cl >> 2)*12 + (cl & 3)*3 + k;
    float s = 0.f;
    for (int t = 0; t < 64; ++t) s += sRed[t][col];
    sWavg[cl*3 + k] = s * (1.f / (float)PRED_);
  }
  __syncthreads();

  // ---- final combine + store ----
  float* __restrict__ outp = out + (size_t)b * PRED_ * C_;
  const int cbase = c0 + tc*4;
  for (int jj = 0; jj < njj; ++jj) {
    const int p = tp + 64*jj;
    float vals[4];
    #pragma unroll
    for (int j = 0; j < 4; ++j) {
      const int cl = tc*4 + j;
      float v = sWavg[cl*3 + 0] * acc[jj][j];
      v = fmaf(sWavg[cl*3 + 1], cr[jj][j], v);
      v = fmaf(sWavg[cl*3 + 2], qv[jj][j], v);
      vals[j] = fmaf(v, std_c[j], mean_c[j]);
    }
    if (cbase + 3 < C_) {
      float2 v01; v01.x = vals[0]; v01.y = vals[1];
      float2 v23; v23.x = vals[2]; v23.y = vals[3];
      *(float2*)&outp[(size_t)p*C_ + cbase]     = v01;
      *(float2*)&outp[(size_t)p*C_ + cbase + 2] = v23;
    } else {
      #pragma unroll
      for (int j = 0; j < 4; ++j)
        if (cbase + j < C_) outp[(size_t)p*C_ + cbase + j] = vals[j];
    }
  }
}

extern "C" void kernel_launch(void* const* d_in, const int* in_sizes, int n_in,
                              void* d_out, int out_size, void* d_ws, size_t ws_size,
                              hipStream_t stream) {
  const float* x        = (const float*)d_in[0];
  const float* x_mark   = (const float*)d_in[1];
  const float* pattern  = (const float*)d_in[2];
  const float* sw       = (const float*)d_in[3];
  const float* sb       = (const float*)d_in[4];
  const float* tw       = (const float*)d_in[5];
  const float* tb       = (const float*)d_in[6];
  const float* w1       = (const float*)d_in[7];
  const float* b1       = (const float*)d_in[8];
  const float* w2       = (const float*)d_in[9];
  const float* b2       = (const float*)d_in[10];
  float* out = (float*)d_out;
  float* ws  = (float*)d_ws;

  // Deterministic across calls (ws_size fixed) -> graph-capture safe.
  const int exact = (ws_size >= (size_t)WS_EXACT_FLOATS * sizeof(float)) ? 1 : 0;

  hipLaunchKernelGGL(prep_w_k, dim3((SEQ_*PRED_ + 255)/256), dim3(256), 0, stream,
                     sw, tw, ws + OFF_WCOMB);
  hipLaunchKernelGGL(prep_small_k, dim3(1), dim3(512), 0, stream,
                     ws + OFF_WCOMB, sb, tb, w1, b1, w2,
                     ws + OFF_COLSUM, ws + OFF_BIAS, ws + OFF_WPACK);
  if (exact) {
    hipLaunchKernelGGL(prep_foldb_k, dim3(B_), dim3(384), 0, stream,
                       ws + OFF_WCOMB, x_mark, ws + OFF_F0B);
  } else {
    hipLaunchKernelGGL(prep_fold_k, dim3((PLEN_*PRED_ + 255)/256), dim3(256), 0, stream,
                       ws + OFF_WCOMB, ws + OFF_F0);
  }
  hipLaunchKernelGGL(fused_k, dim3((C_ + 15)/16, B_), dim3(256), 0, stream,
                     x, x_mark, pattern, ws, b2, out, exact);
}